// Round 2
// baseline (30.226 us; speedup 1.0000x reference)
//
#include <hip/hip_runtime.h>

#define BROWS 8192
#define EPSF 1e-7f
#define NBLK 512          // pair-kernel blocks
#define RPB 16            // rows per pair block

// ws float layout:
//   te        : float2[8192]  -> floats [0, 16384)
//   risk      : [16384, 24576)
//   nll_part  : [24576, 24608)   (32)
//   rank_part : [24608, 25120)   (512)
//   cnt_part  : [25120, 25632)   (512)
//   counter   : int at float-index 25632

__device__ __forceinline__ float wave_reduce_sum(float v) {
    #pragma unroll
    for (int off = 32; off > 0; off >>= 1) v += __shfl_xor(v, off, 64);
    return v;
}

// ---------- Kernel A: per-row NLL + risk + (t, exp(risk)) pairs ----------
__global__ __launch_bounds__(256) void row_kernel(
        const float4* __restrict__ outputs, const float* __restrict__ t,
        const int* __restrict__ y, const int* __restrict__ c,
        float2* __restrict__ te, float* __restrict__ risk,
        float* __restrict__ nll_part, int* __restrict__ counter) {
    __shared__ float s_wave[4];
    int i = blockIdx.x * 256 + threadIdx.x;
    if (i == 0) *counter = 0;              // reset last-block counter each call
    float4 o = outputs[i];

    float h0 = 1.f / (1.f + expf(-o.x));
    float h1 = 1.f / (1.f + expf(-o.y));
    float h2 = 1.f / (1.f + expf(-o.z));
    float h3 = 1.f / (1.f + expf(-o.w));

    float Sp1 = 1.f - h0;
    float Sp2 = Sp1 * (1.f - h1);
    float Sp3 = Sp2 * (1.f - h2);
    float Sp4 = Sp3 * (1.f - h3);

    int yi = y[i];
    float s_prev = (yi == 0) ? 1.f : (yi == 1) ? Sp1 : (yi == 2) ? Sp2 : Sp3;
    float s_this = (yi == 0) ? Sp1 : (yi == 1) ? Sp2 : (yi == 2) ? Sp3 : Sp4;
    float h_this = (yi == 0) ? h0  : (yi == 1) ? h1  : (yi == 2) ? h2  : h3;

    s_prev = fmaxf(s_prev, EPSF);
    s_this = fmaxf(s_this, EPSF);
    h_this = fmaxf(h_this, EPSF);

    float cf = (float)c[i];
    float nll = -cf * logf(s_this) - (1.f - cf) * (logf(s_prev) + logf(h_this));

    float r = -(Sp1 + Sp2 + Sp3 + Sp4);    // risk in (-4, 0)
    risk[i] = r;
    te[i] = make_float2(t[i], expf(r));    // e in [e^-4, 1]: unshifted sums safe

    float ws = wave_reduce_sum(nll);
    int lane = threadIdx.x & 63, wave = threadIdx.x >> 6;
    if (lane == 0) s_wave[wave] = ws;
    __syncthreads();
    if (threadIdx.x == 0)
        nll_part[blockIdx.x] = s_wave[0] + s_wave[1] + s_wave[2] + s_wave[3];
}

// ---------- Kernel B: pairwise masked sums + fused final combine ----------
// Block b owns rows [16b, 16b+16). Wave w loads j-chunk [512w, 512w+512)
// once (8 coalesced b64 loads) and updates 16 register accumulators.
__global__ __launch_bounds__(1024, 4) void pair_kernel(
        const float2* __restrict__ te, const float* __restrict__ t,
        const float* __restrict__ risk, const int* __restrict__ c,
        const float* __restrict__ nll_part, float* __restrict__ rank_part,
        float* __restrict__ cnt_part, int* __restrict__ counter,
        float* __restrict__ out) {
    __shared__ float red[16][64][18];      // [wave][lane][r], pad 18: conflict-free
    __shared__ float s_c[RPB], s_n[RPB];
    __shared__ int s_last;

    int tid = threadIdx.x, wave = tid >> 6, lane = tid & 63;
    int rowbase = blockIdx.x * RPB;

    float tr[RPB];
    #pragma unroll
    for (int r = 0; r < RPB; ++r) tr[r] = t[rowbase + r];   // uniform -> SGPR

    float acc[RPB];
    #pragma unroll
    for (int r = 0; r < RPB; ++r) acc[r] = 0.f;

    const float2* tp = te + wave * 512 + lane;
    #pragma unroll
    for (int k = 0; k < 8; ++k) {
        float2 p = tp[64 * k];             // coalesced, L1/L2-resident
        #pragma unroll
        for (int r = 0; r < RPB; ++r)
            acc[r] += (p.x > tr[r]) ? p.y : 0.f;
    }

    // transpose-reduce: wave r sums row r across all 16 waves x 64 lanes
    float2* rp = (float2*)&red[wave][lane][0];
    #pragma unroll
    for (int h = 0; h < 8; ++h) rp[h] = make_float2(acc[2 * h], acc[2 * h + 1]);
    __syncthreads();

    {
        int r = wave;
        float s = 0.f;
        #pragma unroll
        for (int w = 0; w < 16; ++w) s += red[w][lane][r];
        s = wave_reduce_sum(s);
        if (lane == 0) {
            int row = rowbase + r;
            bool valid = (c[row] == 0) && (s > 0.f);
            s_c[r] = valid ? (logf(s) - risk[row]) : 0.f;
            s_n[r] = valid ? 1.f : 0.f;
        }
    }
    __syncthreads();

    if (tid == 0) {
        float rs = 0.f, cs = 0.f;
        #pragma unroll
        for (int r = 0; r < RPB; ++r) { rs += s_c[r]; cs += s_n[r]; }
        rank_part[blockIdx.x] = rs;
        cnt_part[blockIdx.x]  = cs;
        __threadfence();                    // release partials device-scope
        int old = atomicAdd(counter, 1);
        s_last = (old == NBLK - 1) ? 1 : 0;
    }
    __syncthreads();

    if (s_last) {                           // exactly one block: final combine
        __threadfence();                    // acquire other blocks' partials
        float nll = (tid < 32) ? nll_part[tid] : 0.f;
        float rs  = (tid < NBLK) ? rank_part[tid] : 0.f;
        float cs  = (tid < NBLK) ? cnt_part[tid] : 0.f;
        nll = wave_reduce_sum(nll);
        rs  = wave_reduce_sum(rs);
        cs  = wave_reduce_sum(cs);
        __shared__ float fin[48];
        if (lane == 0) { fin[wave] = nll; fin[16 + wave] = rs; fin[32 + wave] = cs; }
        __syncthreads();
        if (tid == 0) {
            float a = 0.f, b = 0.f, d = 0.f;
            #pragma unroll
            for (int w = 0; w < 16; ++w) { a += fin[w]; b += fin[16 + w]; d += fin[32 + w]; }
            float loss_nll  = a / (float)BROWS;
            float loss_rank = (d > 0.f) ? (b / fmaxf(d, 1.f)) : 0.f;
            out[0] = loss_nll + 0.5f * loss_rank;
        }
    }
}

extern "C" void kernel_launch(void* const* d_in, const int* in_sizes, int n_in,
                              void* d_out, int out_size, void* d_ws, size_t ws_size,
                              hipStream_t stream) {
    const float4* outputs = (const float4*)d_in[0];
    const float*  t       = (const float*)d_in[1];
    const int*    y       = (const int*)d_in[2];
    const int*    c       = (const int*)d_in[3];
    float* out = (float*)d_out;

    float* ws        = (float*)d_ws;
    float2* te       = (float2*)ws;                 // 16384 floats
    float* risk      = ws + 16384;
    float* nll_part  = ws + 24576;
    float* rank_part = ws + 24608;
    float* cnt_part  = ws + 25120;
    int*   counter   = (int*)(ws + 25632);

    row_kernel<<<32, 256, 0, stream>>>(outputs, t, y, c, te, risk, nll_part, counter);
    pair_kernel<<<NBLK, 1024, 0, stream>>>(te, t, risk, c, nll_part,
                                           rank_part, cnt_part, counter, out);
}

// Round 3
// 16.413 us; speedup vs baseline: 1.8416x; 1.8416x over previous
//
#include <hip/hip_runtime.h>

#define BROWS 8192
#define EPSF 1e-7f
#define NBLK 256          // K1 blocks = 1 per CU
#define RPB 32            // rows per block
#define TPB 1024

__device__ __forceinline__ float wave_reduce_sum(float v) {
    #pragma unroll
    for (int off = 32; off > 0; off >>= 1) v += __shfl_xor(v, off, 64);
    return v;
}

__device__ __forceinline__ float rcp_fast(float x) {
    return __builtin_amdgcn_rcpf(x);
}

// ---------- K1: fully fused (redundant e-table per block, no cross-block deps) ----------
// part[b] = {rank_contrib_sum, valid_count, nll_sum, 0} over block b's 32 rows.
__global__ __launch_bounds__(TPB, 4) void fused_kernel(
        const float4* __restrict__ outputs, const float* __restrict__ t,
        const int* __restrict__ y, const int* __restrict__ c,
        float4* __restrict__ part) {
    __shared__ float2 te[BROWS];          // 64 KB: (t_j, e_j) for ALL j
    int tid = threadIdx.x, lane = tid & 63, wave = tid >> 6;
    int rowbase = blockIdx.x * RPB;

    // ---- Phase A: every block computes the full (t, e) table (redundant, parallel) ----
    #pragma unroll
    for (int u = 0; u < BROWS / TPB; ++u) {
        int j = tid + u * TPB;
        float4 o = outputs[j];            // 128 KB, L2-hot across blocks
        // q_i = 1 - sigmoid(x_i) = 1/(1+e^x)
        float q0 = rcp_fast(1.f + __expf(o.x));
        float q1 = rcp_fast(1.f + __expf(o.y));
        float q2 = rcp_fast(1.f + __expf(o.z));
        float q3 = rcp_fast(1.f + __expf(o.w));
        float S1 = q0, S2 = S1 * q1, S3 = S2 * q2, S4 = S3 * q3;
        float risk = -(S1 + S2 + S3 + S4);        // in (-4, 0)
        te[j] = make_float2(t[j], __expf(risk));  // e in [e^-4, 1]: unshifted sums safe
    }
    __syncthreads();

    // ---- Phase B: wave w scans full table for its 2 rows ----
    float t0 = te[rowbase + 2 * wave].x;          // LDS broadcast reads
    float t1 = te[rowbase + 2 * wave + 1].x;
    float a0 = 0.f, a1 = 0.f;
    #pragma unroll 8
    for (int k = lane; k < BROWS; k += 64) {
        float2 p = te[k];                 // ds_read_b64, stride-1: free 2-way alias
        a0 += (p.x > t0) ? p.y : 0.f;
        a1 += (p.x > t1) ? p.y : 0.f;
    }
    a0 = wave_reduce_sum(a0);
    a1 = wave_reduce_sum(a1);
    __syncthreads();                      // all te reads done before reuse

    float* wsum = (float*)te;             // reuse dead LDS: [RPB] row sums
    if (lane == 0) { wsum[2 * wave] = a0; wsum[2 * wave + 1] = a1; }
    __syncthreads();

    // ---- Phase C: wave 0 finishes the block's 32 rows (nll + rank contrib) ----
    if (wave == 0) {
        float contrib = 0.f, cnt = 0.f, nll = 0.f;
        if (lane < RPB) {
            int row = rowbase + lane;
            float s = wsum[lane];                 // sum_{t_j > t_row} e_j
            float4 o = outputs[row];              // L2/L1-hot recompute
            float q0 = rcp_fast(1.f + __expf(o.x));
            float q1 = rcp_fast(1.f + __expf(o.y));
            float q2 = rcp_fast(1.f + __expf(o.z));
            float q3 = rcp_fast(1.f + __expf(o.w));
            float S1 = q0, S2 = S1 * q1, S3 = S2 * q2, S4 = S3 * q3;
            float risk = -(S1 + S2 + S3 + S4);
            int yi = y[row], ci = c[row];
            float s_prev = (yi == 0) ? 1.f : (yi == 1) ? S1 : (yi == 2) ? S2 : S3;
            float s_this = (yi == 0) ? S1  : (yi == 1) ? S2 : (yi == 2) ? S3 : S4;
            float xsel   = (yi == 0) ? o.x : (yi == 1) ? o.y : (yi == 2) ? o.z : o.w;
            float h_this = rcp_fast(1.f + __expf(-xsel));   // direct sigmoid: no cancellation
            float cf = (float)ci;
            nll = -cf * __logf(fmaxf(s_this, EPSF))
                  - (1.f - cf) * (__logf(fmaxf(s_prev, EPSF)) + __logf(fmaxf(h_this, EPSF)));
            bool valid = (ci == 0) && (s > 0.f);  // s>0 <=> any t_j > t_row (e_j >= e^-4)
            contrib = valid ? (__logf(s) - risk) : 0.f;
            cnt     = valid ? 1.f : 0.f;
        }
        contrib = wave_reduce_sum(contrib);
        cnt     = wave_reduce_sum(cnt);
        nll     = wave_reduce_sum(nll);
        if (lane == 0) part[blockIdx.x] = make_float4(contrib, cnt, nll, 0.f);
    }
}

// ---------- K2: deterministic combine of 256 block partials ----------
__global__ __launch_bounds__(NBLK) void combine_kernel(
        const float4* __restrict__ part, float* __restrict__ out) {
    __shared__ float sh[12];
    int tid = threadIdx.x, lane = tid & 63, wave = tid >> 6;  // 4 waves
    float4 p = part[tid];
    float rs = wave_reduce_sum(p.x);
    float cs = wave_reduce_sum(p.y);
    float ns = wave_reduce_sum(p.z);
    if (lane == 0) { sh[wave] = rs; sh[4 + wave] = cs; sh[8 + wave] = ns; }
    __syncthreads();
    if (tid == 0) {
        float b = sh[0] + sh[1] + sh[2] + sh[3];
        float d = sh[4] + sh[5] + sh[6] + sh[7];
        float a = sh[8] + sh[9] + sh[10] + sh[11];
        float loss_nll  = a / (float)BROWS;
        float loss_rank = (d > 0.f) ? (b / fmaxf(d, 1.f)) : 0.f;
        out[0] = loss_nll + 0.5f * loss_rank;
    }
}

extern "C" void kernel_launch(void* const* d_in, const int* in_sizes, int n_in,
                              void* d_out, int out_size, void* d_ws, size_t ws_size,
                              hipStream_t stream) {
    const float4* outputs = (const float4*)d_in[0];
    const float*  t       = (const float*)d_in[1];
    const int*    y       = (const int*)d_in[2];
    const int*    c       = (const int*)d_in[3];
    float* out = (float*)d_out;
    float4* part = (float4*)d_ws;         // 256 * 16 B, fully rewritten each call

    fused_kernel<<<NBLK, TPB, 0, stream>>>(outputs, t, y, c, part);
    combine_kernel<<<1, NBLK, 0, stream>>>(part, out);
}